// Round 17
// baseline (139.748 us; speedup 1.0000x reference)
//

#include <hip/hip_runtime.h>

// RadiusInteractionGraph: B=128 molecules x 512 atoms, K=32 NN, cutoff 10.
// d_out is FLOAT32: [E] src ++ [E] dst ++ [E] weight, E = 128*512*32.
//
// R17 = R15 wave-per-row structure (PASS @ 88us kernel, 95% VALUBusy) + the
// R16 dual-row ILP interleave, with the capture reverted to lane==r cndmask
// (__builtin_amdgcn_writelane does not exist in this toolchain — R16 compile
// fail). Two independent DPP min-reduction chains per wave fill each other's
// read-after-VALU hazard slots.
// Selection semantics identical: key = (d2_hi23 | j) lexicographic ==
// lax.top_k stable order; exact __f*_rn np arithmetic (no FMA contraction —
// cutoff-boundary flips vs the np ref would blow the weight threshold).

constexpr int EDGES = 128 * 512 * 32;   // 2097152

template <int CTRL>
static __device__ __forceinline__ unsigned dpp_min_step(unsigned x) {
    // old = -1 = UINT_MAX = umin identity; bound_ctrl=false.
    int t = __builtin_amdgcn_update_dpp(-1, (int)x, CTRL, 0xF, 0xF, false);
    unsigned u = (unsigned)t;
    return u < x ? u : x;
}

// Reduce to lane 63, return as wave-uniform value (readlane -> SGPR).
static __device__ __forceinline__ unsigned wave_min64_s(unsigned x) {
    x = dpp_min_step<0x111>(x);   // row_shr:1
    x = dpp_min_step<0x112>(x);   // row_shr:2
    x = dpp_min_step<0x114>(x);   // row_shr:4
    x = dpp_min_step<0x118>(x);   // row_shr:8
    x = dpp_min_step<0x142>(x);   // row_bcast:15
    x = dpp_min_step<0x143>(x);   // row_bcast:31
    return (unsigned)__builtin_amdgcn_readlane((int)x, 63);
}

static __device__ __forceinline__ unsigned umin2(unsigned a, unsigned b) {
    return a < b ? a : b;
}

// Build 8 candidate keys for center ci against LDS atoms; per-lane sort-8.
static __device__ __forceinline__ void build_sorted8(const float4* atoms,
                                                     const float4 ci,
                                                     const int i, const int lane,
                                                     unsigned q[8]) {
#pragma unroll
    for (int c = 0; c < 8; ++c) {
        const int j = c * 64 + lane;
        const float4 pj = atoms[j];              // one ds_read_b128
        // np einsum order: ((xi*xj + yi*yj) + zi*zj), plain f32, no fma
        float dot = __fadd_rn(__fadd_rn(__fmul_rn(ci.x, pj.x),
                                        __fmul_rn(ci.y, pj.y)),
                              __fmul_rn(ci.z, pj.z));
        float d2 = __fsub_rn(__fadd_rn(ci.w, pj.w), __fmul_rn(2.0f, dot));
        d2 = fmaxf(d2, 0.0f);
        q[c] = ((j != i) && (d2 <= 100.0f))
                   ? ((__float_as_uint(d2) & 0xFFFFFE00u) | (unsigned)j)
                   : 0xFFFFFFFFu;
    }
#define CE(a_, b_) { unsigned lo = umin2(q[a_], q[b_]); \
                     unsigned hi = q[a_] ^ q[b_] ^ lo;  \
                     q[a_] = lo; q[b_] = hi; }
    CE(0,1) CE(2,3) CE(4,5) CE(6,7)
    CE(0,2) CE(1,3) CE(4,6) CE(5,7)
    CE(1,2) CE(5,6)
    CE(0,4) CE(1,5) CE(2,6) CE(3,7)
    CE(2,4) CE(3,5)
    CE(1,2) CE(3,4) CE(5,6)
#undef CE
}

static __device__ __forceinline__ void emit32(const float4* atoms,
                                              const float4 ci, const int base,
                                              const int gdst, const int lane,
                                              unsigned res,
                                              float* __restrict__ out) {
    if (lane < 32) {
        float w = 0.0f;
        float srcf = (float)gdst;                // pad = self-edge, weight 0
        if (res != 0xFFFFFFFFu) {
            const int j = (int)(res & 511u);
            const float4 pj = atoms[j];
            float dot = __fadd_rn(__fadd_rn(__fmul_rn(ci.x, pj.x),
                                            __fmul_rn(ci.y, pj.y)),
                                  __fmul_rn(ci.z, pj.z));
            float d2 = __fsub_rn(__fadd_rn(ci.w, pj.w), __fmul_rn(2.0f, dot));
            d2 = fmaxf(d2, 0.0f);
            w = __fsqrt_rn(fmaxf(d2, 1e-12f));
            srcf = (float)(base + j);
        }
        const size_t eb = (size_t)gdst * 32 + (size_t)lane;
        out[eb]                     = srcf;          // src
        out[(size_t)EDGES + eb]     = (float)gdst;   // dst
        out[(size_t)EDGES * 2 + eb] = w;             // weight
    }
}

__global__ __launch_bounds__(256)
void RadiusInteractionGraph_73246372266582_kernel(const float* __restrict__ pos,
                                                  float* __restrict__ out) {
    __shared__ float4 atoms[512];     // x, y, z, |p|^2

    const int tid     = threadIdx.x;
    const int b       = blockIdx.x >> 5;          // 32 blocks per molecule
    const int rowbase = (blockIdx.x & 31) * 16;   // 16 rows per block
    const int base    = b * 512;

    for (int a = tid; a < 512; a += 256) {
        float x = pos[(base + a) * 3 + 0];
        float y = pos[(base + a) * 3 + 1];
        float z = pos[(base + a) * 3 + 2];
        // np: sum(p*p) = (x*x + y*y) + z*z, sequential f32, no fma
        float sq = __fadd_rn(__fadd_rn(__fmul_rn(x, x), __fmul_rn(y, y)),
                             __fmul_rn(z, z));
        atoms[a] = make_float4(x, y, z, sq);
    }
    __syncthreads();

    const int wave = tid >> 6;
    const int lane = tid & 63;

    // Two rows per pass: independent min chains interleave to hide DPP
    // dependency bubbles.
    for (int rp = 0; rp < 2; ++rp) {
        const int iA = rowbase + wave * 4 + rp * 2;
        const int iB = iA + 1;
        const float4 cA = atoms[iA];
        const float4 cB = atoms[iB];

        unsigned qA[8], qB[8];
        build_sorted8(atoms, cA, iA, lane, qA);
        build_sorted8(atoms, cB, iB, lane, qB);

        unsigned resA = 0xFFFFFFFFu, resB = 0xFFFFFFFFu;
#pragma unroll
        for (int r = 0; r < 32; ++r) {
            const unsigned mA = wave_min64_s(qA[0]);
            const unsigned mB = wave_min64_s(qB[0]);
            // capture into lane r (shared predicate lane==r for A and B)
            const bool cap = (lane == r);
            resA = cap ? mA : resA;
            resB = cap ? mB : resB;
            // advance the (unique) winner's queue
            const bool aA = (qA[0] == mA);
            const bool aB = (qB[0] == mB);
            qA[0] = aA ? qA[1] : qA[0];  qB[0] = aB ? qB[1] : qB[0];
            qA[1] = aA ? qA[2] : qA[1];  qB[1] = aB ? qB[2] : qB[1];
            qA[2] = aA ? qA[3] : qA[2];  qB[2] = aB ? qB[3] : qB[2];
            qA[3] = aA ? qA[4] : qA[3];  qB[3] = aB ? qB[4] : qB[3];
            qA[4] = aA ? qA[5] : qA[4];  qB[4] = aB ? qB[5] : qB[4];
            qA[5] = aA ? qA[6] : qA[5];  qB[5] = aB ? qB[6] : qB[5];
            qA[6] = aA ? qA[7] : qA[6];  qB[6] = aB ? qB[7] : qB[6];
            qA[7] = aA ? 0xFFFFFFFFu : qA[7];
            qB[7] = aB ? 0xFFFFFFFFu : qB[7];
        }

        emit32(atoms, cA, base, base + iA, lane, resA, out);
        emit32(atoms, cB, base, base + iB, lane, resB, out);
    }
}

extern "C" void kernel_launch(void* const* d_in, const int* in_sizes, int n_in,
                              void* d_out, int out_size, void* d_ws, size_t ws_size,
                              hipStream_t stream) {
    (void)in_sizes; (void)n_in; (void)d_ws; (void)ws_size; (void)out_size;
    const float* pos = (const float*)d_in[0];   // [N,3] f32
    float* out       = (float*)d_out;           // [3E] f32

    RadiusInteractionGraph_73246372266582_kernel<<<dim3(4096), dim3(256), 0,
                                                   stream>>>(pos, out);
}
